// Round 7
// baseline (402.812 us; speedup 1.0000x reference)
//
#include <hip/hip_runtime.h>

// CapsNet dynamic routing — fp32 in / fp32 out.
// Ladder: R0 66.3 -> R5 61.0 (ci phase rotation) -> R6 54.4 us/pass (rotation
// fixed to ch%12 restoring by-sibling L2 W-reuse, FETCH 64->22 MB; x moved to
// scalar pipe via s_load_dwordx8, halving LDS ops). R7:
// (a) register-prefetch W pipeline — R1's idea, which spilled at VGPR cap 168
//     when base pressure was ~143; R6's scalar-x base is 76 VGPR, so tmp[8]
//     (+32) now fits with ~60 headroom. Issue next-ci loads right after
//     barrier A; they fly across the whole compute phase; the ds_write at the
//     top of the next ci finds vmcnt already satisfied -> stage latency and
//     the load->drain->write chain leave the per-ci critical path.
// (b) squash widened 4x: was 16K threads x 96-deep strided reduction
//     (latency-bound, ~10-15 us each, ~25% of total runtime); now 256x256 =
//     65K threads, 4 threads/item x 24 chunks, combined with shfl_xor(1,2)
//     (ch-split) then shfl_xor(4,8) (d-quad for s2). BW-bound ~4 us.
// Spill alarm (R1/R4 lesson): WRITE_SIZE must stay <= ~43 MB and VGPR 100-130.
// B=64, Ni=1152, Di=8, No=64, Do=16.
// u[b,i,o,d] = sum_k W[i*8192 + (o*16+d)*8 + k] * x[b*9216 + i*8 + k]
// it0: c=1/64       -> s0 -> v0
// it1: l=<u,v0>     -> c1 -> s1 -> v1
// it2: l=<u,v0+v1>  -> c2 (OUT [B,Ni,No]) -> s2 -> v2 (OUT [B,No,Do])

#define B_      64
#define NI_     1152
#define DI_     8
#define NO_     64
#define DO_     16
#define NOD_    1024
#define CH_     96
#define CI_     12
#define BG_     8
#define BSPLIT_ 8
#define V_ELEMS 65536
#define PADR    33      // float4 slots per o-row in LDS tile (132 floats)

static_assert(CH_ * CI_ == NI_, "chunking");
static_assert(BG_ * BSPLIT_ == B_, "b split");

typedef __attribute__((ext_vector_type(8))) float f8v;

// MODE 0: c=1/64 (applied in squash), acc sum_i u       -> part
// MODE 1: l=<u,v0>, softmax over o, acc c*u             -> part
// MODE 2: l=<u,v0+v1>, softmax, write c (fp32), acc c*u -> part
template <int MODE>
__global__ __launch_bounds__(256, 3)
void caps_pass(const float* __restrict__ X,
               const float* __restrict__ W,
               const float* __restrict__ vin,
               float* __restrict__ part,
               float* __restrict__ rw)
{
    __shared__ float4 wtile[NO_ * PADR];       // 33 KB padded W[i] tile
    __shared__ float  e_lds[BG_][NO_];         // 2 KB
    __shared__ float  invS[BG_];

    const int t  = threadIdx.x;
    const int o  = t >> 2, q = t & 3;
    const int ch = blockIdx.x;            // same-ch blocks 96 apart -> same XCD
    const int by = blockIdx.y;
    const int b0 = by * BG_;
    const int i0 = ch * CI_;

    // phase = ch%12: co-resident blocks (linear +-256 => ch +-64/32) get
    // phases {0,4,8} — de-lockstepped; by-siblings (same ch) stay in the
    // SAME phase so all 8 read the same W[i] simultaneously (L2 reuse).
    const int phase = ch % CI_;

    const float4* Wq = (const float4*)W;

    int ci = phase;

    // ---- pipeline prologue: prefetch W[i0+phase] into registers ----
    float4 tmp[8];
    {
        const float4* wg = Wq + (size_t)(i0 + ci) * 2048;
#pragma unroll
        for (int j = 0; j < 8; ++j) tmp[j] = wg[t + 256 * j];
    }

    // routing vector -> registers: v[b][o*16 + q*4 + j]  (coalesced: addr = 4t)
    float vreg[BG_][4];
    if (MODE >= 1) {
#pragma unroll
        for (int b = 0; b < BG_; ++b) {
            float4 qv = *((const float4*)(vin + (size_t)(b0 + b) * NOD_ + 4 * t));
            vreg[b][0]=qv.x; vreg[b][1]=qv.y; vreg[b][2]=qv.z; vreg[b][3]=qv.w;
        }
    }

    float acc[BG_][4];
#pragma unroll
    for (int b = 0; b < BG_; ++b) { acc[b][0]=0.f; acc[b][1]=0.f; acc[b][2]=0.f; acc[b][3]=0.f; }

    for (int cc = 0; cc < CI_; ++cc) {
        const int i = i0 + ci;

        // ---- write prefetched W[i] to padded tile. vmcnt wait for tmp was
        //      satisfied during the previous iteration's compute (pipeline).
        //      Overwrite safety: all tile reads of iter cc-1 precede that
        //      iter's barrier B/C (or MODE-0 end barrier). ----
#pragma unroll
        for (int j = 0; j < 8; ++j) {
            const int f = t + 256 * j;                    // linear float4 idx
            wtile[(f >> 5) * PADR + (f & 31)] = tmp[j];   // padded row
        }
        __syncthreads();   // A: tile ready

        // ---- issue prefetch of next tile; in flight across whole compute ----
        const int cin = (ci + 1 == CI_) ? 0 : ci + 1;
        if (cc + 1 < CI_) {
            const float4* wg = Wq + (size_t)(i0 + cin) * 2048;
#pragma unroll
            for (int j = 0; j < 8; ++j) tmp[j] = wg[t + 256 * j];
        }

        // ---- wf = W[i][o][4q+jj][0..7] via 8 b128 reads (bank-optimal) ----
        // Issued BEFORE the x s_loads so LDS latency overlaps scalar latency.
        float wf[4][8];
#pragma unroll
        for (int jj = 0; jj < 4; ++jj) {
            float4 a0 = wtile[o * PADR + (4 * q + jj) * 2];
            float4 a1 = wtile[o * PADR + (4 * q + jj) * 2 + 1];
            wf[jj][0]=a0.x; wf[jj][1]=a0.y; wf[jj][2]=a0.z; wf[jj][3]=a0.w;
            wf[jj][4]=a1.x; wf[jj][5]=a1.y; wf[jj][6]=a1.z; wf[jj][7]=a1.w;
        }

        // ---- x[b0..b0+7][i][0..7] via scalar pipe: 8x s_load_dwordx8 ----
        // Block-uniform data; one self-contained asm (loads + wait) keeps the
        // compiler's lgkm accounting valid. lgkmcnt(0) also covers the wf
        // ds_reads above (their data is needed right after anyway); it does
        // NOT touch vmcnt, so the tmp prefetch stays in flight.
        f8v xs0, xs1, xs2, xs3, xs4, xs5, xs6, xs7;
        {
            const float* xp  = X + ((size_t)b0 * NI_ + i) * DI_;
            const float* xp4 = xp + 4 * (size_t)NI_ * DI_;
            asm volatile(
                "s_load_dwordx8 %0, %8, 0\n\t"
                "s_load_dwordx8 %1, %8, 36864\n\t"
                "s_load_dwordx8 %2, %8, 73728\n\t"
                "s_load_dwordx8 %3, %8, 110592\n\t"
                "s_load_dwordx8 %4, %9, 0\n\t"
                "s_load_dwordx8 %5, %9, 36864\n\t"
                "s_load_dwordx8 %6, %9, 73728\n\t"
                "s_load_dwordx8 %7, %9, 110592\n\t"
                "s_waitcnt lgkmcnt(0)"
                : "=&s"(xs0), "=&s"(xs1), "=&s"(xs2), "=&s"(xs3),
                  "=&s"(xs4), "=&s"(xs5), "=&s"(xs6), "=&s"(xs7)
                : "s"(xp), "s"(xp4)
                : "memory");
        }

        float u[BG_][4];
#pragma unroll
        for (int b = 0; b < BG_; ++b) {
            const f8v xv = (b==0)?xs0:(b==1)?xs1:(b==2)?xs2:(b==3)?xs3
                         :(b==4)?xs4:(b==5)?xs5:(b==6)?xs6:xs7;   // folds at unroll
#pragma unroll
            for (int jj = 0; jj < 4; ++jj) {
                float s = wf[jj][0] * xv[0];
                s = fmaf(wf[jj][1], xv[1], s); s = fmaf(wf[jj][2], xv[2], s);
                s = fmaf(wf[jj][3], xv[3], s); s = fmaf(wf[jj][4], xv[4], s);
                s = fmaf(wf[jj][5], xv[5], s); s = fmaf(wf[jj][6], xv[6], s);
                s = fmaf(wf[jj][7], xv[7], s);
                u[b][jj] = s;
            }
            if (MODE >= 1) {
                float a = u[b][0]*vreg[b][0] + u[b][1]*vreg[b][1]
                        + u[b][2]*vreg[b][2] + u[b][3]*vreg[b][3];
                a += __shfl_xor(a, 1);
                a += __shfl_xor(a, 2);          // full 16-d dot within quad
                if (q == 0) e_lds[b][o] = __expf(a);
            } else {
                acc[b][0]+=u[b][0]; acc[b][1]+=u[b][1];
                acc[b][2]+=u[b][2]; acc[b][3]+=u[b][3];
            }
        }

        if (MODE >= 1) {
            __syncthreads();   // B: e_lds complete (also fences tile reads)
            {
                const int bb = t >> 5, l = t & 31;
                float s = e_lds[bb][l] + e_lds[bb][l + 32];
                s += __shfl_xor(s, 1);  s += __shfl_xor(s, 2);  s += __shfl_xor(s, 4);
                s += __shfl_xor(s, 8);  s += __shfl_xor(s, 16);
                if (l == 0) invS[bb] = 1.0f / s;
            }
            __syncthreads();   // C: invS ready
#pragma unroll
            for (int b = 0; b < BG_; ++b) {
                const float c = e_lds[b][o] * invS[b];
                acc[b][0] = fmaf(c, u[b][0], acc[b][0]);
                acc[b][1] = fmaf(c, u[b][1], acc[b][1]);
                acc[b][2] = fmaf(c, u[b][2], acc[b][2]);
                acc[b][3] = fmaf(c, u[b][3], acc[b][3]);
                if (MODE == 2 && q == 0)
                    rw[((size_t)(b0 + b) * NI_ + i) * NO_ + o] = c;
            }
        } else {
            __syncthreads();   // MODE 0: fence tile reads before next overwrite
        }

        ci = cin;
    }

    // partial s: part[b][ch][4t..4t+3] (coalesced float4)
#pragma unroll
    for (int b = 0; b < BG_; ++b) {
        float4 val;
        val.x=acc[b][0]; val.y=acc[b][1]; val.z=acc[b][2]; val.w=acc[b][3];
        *((float4*)(part + (((size_t)(b0 + b) * CH_ + ch) * NOD_ + 4 * t))) = val;
    }
}

// Reduce partials over CH_ chunks, squash over d, emit v.  R7: 4 threads per
// output item (each sums 24 of 96 chunks), combine via shfl_xor(1,2); s2 over
// the 16-d capsule via shfl_xor(4,8) across the 4 dq-items of the same o.
// 256 blocks x 256 threads = 65K threads -> BW-bound (~4 us) instead of the
// old 16K-thread latency-bound version.
// MODE 0: s*=1/64 -> v0 | MODE 1: w01 = v0 + squash(s1) | MODE 2: v2 -> d_out
template <int MODE>
__global__ __launch_bounds__(256)
void caps_squash(const float* __restrict__ part, const float* __restrict__ v0in,
                 float* __restrict__ vout)
{
    const int t  = threadIdx.x;
    const int li = t >> 2, g = t & 3;
    const int c4 = blockIdx.x * 64 + li;     // 0..16383: b*256 + o*4 + dq
    const int b = c4 >> 8, od4 = c4 & 255;
    const float4* p = (const float4*)part + ((size_t)b * CH_ + (size_t)g * 24) * 256 + od4;
    float4 s = {0.f, 0.f, 0.f, 0.f};
#pragma unroll
    for (int cc = 0; cc < 24; ++cc) {
        float4 qv = p[(size_t)cc * 256];
        s.x += qv.x; s.y += qv.y; s.z += qv.z; s.w += qv.w;
    }
    // combine the 4 ch-splits (lanes g=0..3 adjacent)
    s.x += __shfl_xor(s.x, 1); s.y += __shfl_xor(s.y, 1);
    s.z += __shfl_xor(s.z, 1); s.w += __shfl_xor(s.w, 1);
    s.x += __shfl_xor(s.x, 2); s.y += __shfl_xor(s.y, 2);
    s.z += __shfl_xor(s.z, 2); s.w += __shfl_xor(s.w, 2);
    if (MODE == 0) { s.x*=(1.f/64.f); s.y*=(1.f/64.f); s.z*=(1.f/64.f); s.w*=(1.f/64.f); }
    float s2 = s.x*s.x + s.y*s.y + s.z*s.z + s.w*s.w;
    // sum over the 16-d capsule: dq items are li+-1,2 == lanes t+-4,8
    s2 += __shfl_xor(s2, 4); s2 += __shfl_xor(s2, 8);
    const float scale = s2 / ((1.0f + s2) * sqrtf(s2 + 1e-7f));
    if (g == 0) {
        float4 v; v.x = scale*s.x; v.y = scale*s.y; v.z = scale*s.z; v.w = scale*s.w;
        if (MODE == 1) {
            float4 v0 = ((const float4*)v0in)[c4];
            v.x += v0.x; v.y += v0.y; v.z += v0.z; v.w += v0.w;
        }
        ((float4*)vout)[c4] = v;
    }
}

// Safety fallback (R11's passing kernel) — only if ws is unexpectedly tiny.
__global__ __launch_bounds__(1024, 1)
void caps_naive(const float* __restrict__ X, const float* __restrict__ W,
                float* __restrict__ outv, float* __restrict__ outc)
{
    __shared__ float xs[NI_ * DI_];
    __shared__ float agree[NO_];
    __shared__ float expo[NO_];
    __shared__ float s2sh[NO_];
    __shared__ float den;

    const int b = blockIdx.x, tid = threadIdx.x;
    const int o = tid >> 4, d = tid & 15;

    for (int f = tid; f < NI_ * DI_; f += 1024)
        xs[f] = X[(size_t)b * NI_ * DI_ + f];
    __syncthreads();

    float vprev = 0.f, v0 = 0.f, vout = 0.f;
    for (int phase = 0; phase < 3; ++phase) {
        float sacc = 0.f;
        for (int i = 0; i < NI_; ++i) {
            const float* wp = W + (size_t)i * 8192 + (size_t)tid * 8;
            const float* xp = xs + i * DI_;
            float u = 0.f;
#pragma unroll
            for (int k = 0; k < 8; ++k) u = fmaf(wp[k], xp[k], u);
            if (phase == 0) { sacc += u; continue; }
            if (d == 0) agree[o] = 0.f;
            __syncthreads();
            atomicAdd(&agree[o], u * vprev);
            __syncthreads();
            if (tid == 0) den = 0.f;
            __syncthreads();
            if (d == 0) { float e = __expf(agree[o]); expo[o] = e; atomicAdd(&den, e); }
            __syncthreads();
            float c = expo[o] / den;
            sacc = fmaf(c, u, sacc);
            if (phase == 2 && d == 0)
                outc[((size_t)b * NI_ + i) * NO_ + o] = c;
            __syncthreads();
        }
        if (phase == 0) sacc *= (1.0f / 64.0f);
        if (d == 0) s2sh[o] = 0.f;
        __syncthreads();
        atomicAdd(&s2sh[o], sacc * sacc);
        __syncthreads();
        const float s2 = s2sh[o];
        const float scale = s2 / ((1.0f + s2) * sqrtf(s2 + 1e-7f));
        const float vv = scale * sacc;
        if (phase == 0)      { v0 = vv; vprev = vv; }
        else if (phase == 1) { vprev = v0 + vv; }
        else                 { vout = vv; }
        __syncthreads();
    }
    outv[(size_t)b * (NO_ * DO_) + tid] = vout;
}

extern "C" void kernel_launch(void* const* d_in, const int* in_sizes, int n_in,
                              void* d_out, int out_size, void* d_ws, size_t ws_size,
                              hipStream_t stream)
{
    const float *X, *W;
    if (in_sizes[0] < in_sizes[1]) { X = (const float*)d_in[0]; W = (const float*)d_in[1]; }
    else                           { X = (const float*)d_in[1]; W = (const float*)d_in[0]; }

    float* out  = (float*)d_out;
    float* outv = out;             // v: [B,No,Do] fp32
    float* outc = out + V_ELEMS;   // c: [B,Ni,No] fp32

    const size_t needBig = ((size_t)B_ * CH_ * NOD_ + 2 * (size_t)B_ * NOD_) * sizeof(float);
    if (ws_size < needBig) {       // never expected (ws >= 64 MB measured R12)
        caps_naive<<<B_, 1024, 0, stream>>>(X, W, outv, outc);
        return;
    }

    float* part = (float*)d_ws;                      // 25.2 MB
    float* v0   = part + (size_t)B_ * CH_ * NOD_;
    float* w01  = v0 + (size_t)B_ * NOD_;

    dim3 gP(CH_, BSPLIT_), blk(256), gS(256), blkS(256);
    caps_pass<0><<<gP, blk, 0, stream>>>(X, W, nullptr, part, nullptr);
    caps_squash<0><<<gS, blkS, 0, stream>>>(part, nullptr, v0);
    caps_pass<1><<<gP, blk, 0, stream>>>(X, W, v0, part, nullptr);
    caps_squash<1><<<gS, blkS, 0, stream>>>(part, v0, w01);
    caps_pass<2><<<gP, blk, 0, stream>>>(X, W, w01, part, outc);
    caps_squash<2><<<gS, blkS, 0, stream>>>(part, nullptr, outv);
}

// Round 8
// 206.615 us; speedup vs baseline: 1.9496x; 1.9496x over previous
//
#include <hip/hip_runtime.h>

// CapsNet dynamic routing — fp32 in / fp32 out.
// Ladder: R0 66.3 -> R5 61.0 (ci phase rotation) -> R6 54.4 us/pass (ch%12
// rotation + scalar-pipe x) -> R8 (this): per-WAVE-private W slices staged by
// global_load_lds (zero VGPRs — the reg-prefetch spilled identically in
// R1/R4/R7: never hold a 32-VGPR prefetch across compute at the 3-wave cap).
// Key insight: thread t reads only W rows o=t>>2 in [16w,16w+16) — the tile
// quarter its own wave stages. Wave-private slice => NO barrier A at all;
// WAR by program order (ds_read -> lgkmcnt(0) -> issue next DMA). Depth-2
// pipeline in a SINGLE 32 KB buffer: DMA for ci+1 flies over FMA+softmax.
// Swizzle (rule 21, both sides): linear LDS dest; source slot f^((f>>5)&7)
// (XOR const per half-wave -> coalesced); read addr s^(o_local&7) -> 8 lanes
// per 4-bank group = 2-way = free. Deletes 8 ds_write/thread/ci too.
// MODE0: zero barriers in loop. MODE>=1: raw lgkm-only barriers B/C (DMA in
// flight across them) + parity-dbuf e_lds/invS (closes WAR that barrier A
// used to cover). Squash stays R7-widened (4 thr/item, 65K threads).
// B=64, Ni=1152, Di=8, No=64, Do=16.
// u[b,i,o,d] = sum_k W[i*8192 + (o*16+d)*8 + k] * x[b*9216 + i*8 + k]
// it0: c=1/64       -> s0 -> v0
// it1: l=<u,v0>     -> c1 -> s1 -> v1
// it2: l=<u,v0+v1>  -> c2 (OUT [B,Ni,No]) -> s2 -> v2 (OUT [B,No,Do])

#define B_      64
#define NI_     1152
#define DI_     8
#define NO_     64
#define DO_     16
#define NOD_    1024
#define CH_     96
#define CI_     12
#define BG_     8
#define BSPLIT_ 8
#define V_ELEMS 65536

static_assert(CH_ * CI_ == NI_, "chunking");
static_assert(BG_ * BSPLIT_ == B_, "b split");

typedef __attribute__((ext_vector_type(8))) float f8v;

__device__ __forceinline__ void gload_lds16(const float4* g, float4* l)
{
    __builtin_amdgcn_global_load_lds(
        (const __attribute__((address_space(1))) void*)g,
        (__attribute__((address_space(3))) void*)l,
        16 /*bytes*/, 0 /*offset*/, 0 /*aux*/);
}

#define RAW_BARRIER() do { \
    asm volatile("s_waitcnt lgkmcnt(0)" ::: "memory"); \
    __builtin_amdgcn_s_barrier(); \
    __builtin_amdgcn_sched_barrier(0); } while (0)

// MODE 0: c=1/64 (applied in squash), acc sum_i u       -> part
// MODE 1: l=<u,v0>, softmax over o, acc c*u             -> part
// MODE 2: l=<u,v0+v1>, softmax, write c (fp32), acc c*u -> part
template <int MODE>
__global__ __launch_bounds__(256, 3)
void caps_pass(const float* __restrict__ X,
               const float* __restrict__ W,
               const float* __restrict__ vin,
               float* __restrict__ part,
               float* __restrict__ rw)
{
    __shared__ float4 wslice[4][512];          // 32 KB: per-wave W quarter
    __shared__ float  e_lds[2][BG_][NO_];      // 4 KB parity dbuf
    __shared__ float  invS[2][BG_];

    const int t  = threadIdx.x;
    const int w  = t >> 6, l = t & 63;
    const int o  = t >> 2, q = t & 3;          // o in [0,64): wave w -> [16w,16w+16)
    const int ol = l >> 2;                     // o_local in [0,16)
    const int ch = blockIdx.x;            // same-ch blocks 96 apart -> same XCD
    const int by = blockIdx.y;
    const int b0 = by * BG_;
    const int i0 = ch * CI_;

    // phase = ch%12: co-resident blocks (linear +-256 => ch +-64/32) get
    // phases {p,p+4,p+8} — de-lockstepped; by-siblings (same ch) stay in the
    // SAME phase so all 8 read the same W[i] simultaneously (L2 reuse).
    const int phase = ch % CI_;

    const float4* Wq = (const float4*)W;

    // routing vector -> registers: v[b][o*16 + q*4 + j]  (coalesced: addr = 4t)
    float vreg[BG_][4];
    if (MODE >= 1) {
#pragma unroll
        for (int b = 0; b < BG_; ++b) {
            float4 qv = *((const float4*)(vin + (size_t)(b0 + b) * NOD_ + 4 * t));
            vreg[b][0]=qv.x; vreg[b][1]=qv.y; vreg[b][2]=qv.z; vreg[b][3]=qv.w;
        }
    }

    float acc[BG_][4];
#pragma unroll
    for (int b = 0; b < BG_; ++b) { acc[b][0]=0.f; acc[b][1]=0.f; acc[b][2]=0.f; acc[b][3]=0.f; }

    int ci = phase;

    // ---- prologue: DMA-stage this wave's quarter of W[i0+phase] ----
    {
        const float4* src = Wq + (size_t)(i0 + ci) * 2048 + (size_t)w * 512;
#pragma unroll
        for (int j = 0; j < 8; ++j) {
            const int f = j * 64 + l;
            const int g = f ^ ((f >> 5) & 7);      // inverse-swizzled source
            gload_lds16(src + g, &wslice[w][j * 64]);
        }
    }

    for (int cc = 0; cc < CI_; ++cc) {
        const int i   = i0 + ci;
        const int par = cc & 1;
        const int cin = (ci + 1 == CI_) ? 0 : ci + 1;

        // wait own wave's DMAs (issued a full compute phase ago after iter 0)
        asm volatile("s_waitcnt vmcnt(0)" ::: "memory");
        __builtin_amdgcn_sched_barrier(0);

        // ---- wf = W[i][o][4q+jj][0..7] via swizzled b128 reads (2-way, free) ----
        float wf[4][8];
        {
            const int sw = ol & 7;
            const int srow = ol * 32 + 8 * q;
#pragma unroll
            for (int jj = 0; jj < 4; ++jj) {
                float4 a0 = wslice[w][(srow + 2 * jj)     ^ sw];
                float4 a1 = wslice[w][(srow + 2 * jj + 1) ^ sw];
                wf[jj][0]=a0.x; wf[jj][1]=a0.y; wf[jj][2]=a0.z; wf[jj][3]=a0.w;
                wf[jj][4]=a1.x; wf[jj][5]=a1.y; wf[jj][6]=a1.z; wf[jj][7]=a1.w;
            }
        }

        // ---- x[b0..b0+7][i][0..7] via scalar pipe: 8x s_load_dwordx8 ----
        // Self-contained asm; its lgkmcnt(0) also drains the wf ds_reads, so
        // after this point the slice is free to be overwritten. vmcnt untouched.
        f8v xs0, xs1, xs2, xs3, xs4, xs5, xs6, xs7;
        {
            const float* xp  = X + ((size_t)b0 * NI_ + i) * DI_;
            const float* xp4 = xp + 4 * (size_t)NI_ * DI_;
            asm volatile(
                "s_load_dwordx8 %0, %8, 0\n\t"
                "s_load_dwordx8 %1, %8, 36864\n\t"
                "s_load_dwordx8 %2, %8, 73728\n\t"
                "s_load_dwordx8 %3, %8, 110592\n\t"
                "s_load_dwordx8 %4, %9, 0\n\t"
                "s_load_dwordx8 %5, %9, 36864\n\t"
                "s_load_dwordx8 %6, %9, 73728\n\t"
                "s_load_dwordx8 %7, %9, 110592\n\t"
                "s_waitcnt lgkmcnt(0)"
                : "=&s"(xs0), "=&s"(xs1), "=&s"(xs2), "=&s"(xs3),
                  "=&s"(xs4), "=&s"(xs5), "=&s"(xs6), "=&s"(xs7)
                : "s"(xp), "s"(xp4)
                : "memory");
        }
        __builtin_amdgcn_sched_barrier(0);   // pin reads above, DMA below

        // ---- issue next tile's DMA NOW: flies across FMA + softmax phases.
        //      Wave-private slice: WAR closed by the lgkmcnt(0) just above. ----
        if (cc + 1 < CI_) {
            const float4* src = Wq + (size_t)(i0 + cin) * 2048 + (size_t)w * 512;
#pragma unroll
            for (int j = 0; j < 8; ++j) {
                const int f = j * 64 + l;
                const int g = f ^ ((f >> 5) & 7);
                gload_lds16(src + g, &wslice[w][j * 64]);
            }
        }

        float u[BG_][4];
#pragma unroll
        for (int b = 0; b < BG_; ++b) {
            const f8v xv = (b==0)?xs0:(b==1)?xs1:(b==2)?xs2:(b==3)?xs3
                         :(b==4)?xs4:(b==5)?xs5:(b==6)?xs6:xs7;   // folds at unroll
#pragma unroll
            for (int jj = 0; jj < 4; ++jj) {
                float s = wf[jj][0] * xv[0];
                s = fmaf(wf[jj][1], xv[1], s); s = fmaf(wf[jj][2], xv[2], s);
                s = fmaf(wf[jj][3], xv[3], s); s = fmaf(wf[jj][4], xv[4], s);
                s = fmaf(wf[jj][5], xv[5], s); s = fmaf(wf[jj][6], xv[6], s);
                s = fmaf(wf[jj][7], xv[7], s);
                u[b][jj] = s;
            }
            if (MODE >= 1) {
                float a = u[b][0]*vreg[b][0] + u[b][1]*vreg[b][1]
                        + u[b][2]*vreg[b][2] + u[b][3]*vreg[b][3];
                a += __shfl_xor(a, 1);
                a += __shfl_xor(a, 2);          // full 16-d dot within quad
                if (q == 0) e_lds[par][b][o] = __expf(a);
            } else {
                acc[b][0]+=u[b][0]; acc[b][1]+=u[b][1];
                acc[b][2]+=u[b][2]; acc[b][3]+=u[b][3];
            }
        }

        if (MODE >= 1) {
            RAW_BARRIER();   // B: e_lds[par] complete (lgkm only — DMA in flight)
            {
                const int bb = t >> 5, ll = t & 31;
                float s = e_lds[par][bb][ll] + e_lds[par][bb][ll + 32];
                s += __shfl_xor(s, 1);  s += __shfl_xor(s, 2);  s += __shfl_xor(s, 4);
                s += __shfl_xor(s, 8);  s += __shfl_xor(s, 16);
                if (ll == 0) invS[par][bb] = 1.0f / s;
            }
            RAW_BARRIER();   // C: invS ready
#pragma unroll
            for (int b = 0; b < BG_; ++b) {
                const float c = e_lds[par][b][o] * invS[par][b];
                acc[b][0] = fmaf(c, u[b][0], acc[b][0]);
                acc[b][1] = fmaf(c, u[b][1], acc[b][1]);
                acc[b][2] = fmaf(c, u[b][2], acc[b][2]);
                acc[b][3] = fmaf(c, u[b][3], acc[b][3]);
                if (MODE == 2 && q == 0)
                    rw[((size_t)(b0 + b) * NI_ + i) * NO_ + o] = c;
            }
            // next ci uses e_lds[par^1] — parity dbuf closes the WAR.
        }
        // MODE 0: no barriers at all — slice is wave-private.

        ci = cin;
    }

    // partial s: part[b][ch][4t..4t+3] (coalesced float4)
#pragma unroll
    for (int b = 0; b < BG_; ++b) {
        float4 val;
        val.x=acc[b][0]; val.y=acc[b][1]; val.z=acc[b][2]; val.w=acc[b][3];
        *((float4*)(part + (((size_t)(b0 + b) * CH_ + ch) * NOD_ + 4 * t))) = val;
    }
}

// Reduce partials over CH_ chunks, squash over d, emit v.  4 threads per
// output item (each sums 24 of 96 chunks), combine via shfl_xor(1,2); s2 over
// the 16-d capsule via shfl_xor(4,8) across the 4 dq-items of the same o.
// MODE 0: s*=1/64 -> v0 | MODE 1: w01 = v0 + squash(s1) | MODE 2: v2 -> d_out
template <int MODE>
__global__ __launch_bounds__(256)
void caps_squash(const float* __restrict__ part, const float* __restrict__ v0in,
                 float* __restrict__ vout)
{
    const int t  = threadIdx.x;
    const int li = t >> 2, g = t & 3;
    const int c4 = blockIdx.x * 64 + li;     // 0..16383: b*256 + o*4 + dq
    const int b = c4 >> 8, od4 = c4 & 255;
    const float4* p = (const float4*)part + ((size_t)b * CH_ + (size_t)g * 24) * 256 + od4;
    float4 s = {0.f, 0.f, 0.f, 0.f};
#pragma unroll
    for (int cc = 0; cc < 24; ++cc) {
        float4 qv = p[(size_t)cc * 256];
        s.x += qv.x; s.y += qv.y; s.z += qv.z; s.w += qv.w;
    }
    // combine the 4 ch-splits (lanes g=0..3 adjacent)
    s.x += __shfl_xor(s.x, 1); s.y += __shfl_xor(s.y, 1);
    s.z += __shfl_xor(s.z, 1); s.w += __shfl_xor(s.w, 1);
    s.x += __shfl_xor(s.x, 2); s.y += __shfl_xor(s.y, 2);
    s.z += __shfl_xor(s.z, 2); s.w += __shfl_xor(s.w, 2);
    if (MODE == 0) { s.x*=(1.f/64.f); s.y*=(1.f/64.f); s.z*=(1.f/64.f); s.w*=(1.f/64.f); }
    float s2 = s.x*s.x + s.y*s.y + s.z*s.z + s.w*s.w;
    // sum over the 16-d capsule: dq items are li+-1,2 == lanes t+-4,8
    s2 += __shfl_xor(s2, 4); s2 += __shfl_xor(s2, 8);
    const float scale = s2 / ((1.0f + s2) * sqrtf(s2 + 1e-7f));
    if (g == 0) {
        float4 v; v.x = scale*s.x; v.y = scale*s.y; v.z = scale*s.z; v.w = scale*s.w;
        if (MODE == 1) {
            float4 v0 = ((const float4*)v0in)[c4];
            v.x += v0.x; v.y += v0.y; v.z += v0.z; v.w += v0.w;
        }
        ((float4*)vout)[c4] = v;
    }
}

// Safety fallback (R11's passing kernel) — only if ws is unexpectedly tiny.
__global__ __launch_bounds__(1024, 1)
void caps_naive(const float* __restrict__ X, const float* __restrict__ W,
                float* __restrict__ outv, float* __restrict__ outc)
{
    __shared__ float xs[NI_ * DI_];
    __shared__ float agree[NO_];
    __shared__ float expo[NO_];
    __shared__ float s2sh[NO_];
    __shared__ float den;

    const int b = blockIdx.x, tid = threadIdx.x;
    const int o = tid >> 4, d = tid & 15;

    for (int f = tid; f < NI_ * DI_; f += 1024)
        xs[f] = X[(size_t)b * NI_ * DI_ + f];
    __syncthreads();

    float vprev = 0.f, v0 = 0.f, vout = 0.f;
    for (int phase = 0; phase < 3; ++phase) {
        float sacc = 0.f;
        for (int i = 0; i < NI_; ++i) {
            const float* wp = W + (size_t)i * 8192 + (size_t)tid * 8;
            const float* xp = xs + i * DI_;
            float u = 0.f;
#pragma unroll
            for (int k = 0; k < 8; ++k) u = fmaf(wp[k], xp[k], u);
            if (phase == 0) { sacc += u; continue; }
            if (d == 0) agree[o] = 0.f;
            __syncthreads();
            atomicAdd(&agree[o], u * vprev);
            __syncthreads();
            if (tid == 0) den = 0.f;
            __syncthreads();
            if (d == 0) { float e = __expf(agree[o]); expo[o] = e; atomicAdd(&den, e); }
            __syncthreads();
            float c = expo[o] / den;
            sacc = fmaf(c, u, sacc);
            if (phase == 2 && d == 0)
                outc[((size_t)b * NI_ + i) * NO_ + o] = c;
            __syncthreads();
        }
        if (phase == 0) sacc *= (1.0f / 64.0f);
        if (d == 0) s2sh[o] = 0.f;
        __syncthreads();
        atomicAdd(&s2sh[o], sacc * sacc);
        __syncthreads();
        const float s2 = s2sh[o];
        const float scale = s2 / ((1.0f + s2) * sqrtf(s2 + 1e-7f));
        const float vv = scale * sacc;
        if (phase == 0)      { v0 = vv; vprev = vv; }
        else if (phase == 1) { vprev = v0 + vv; }
        else                 { vout = vv; }
        __syncthreads();
    }
    outv[(size_t)b * (NO_ * DO_) + tid] = vout;
}

extern "C" void kernel_launch(void* const* d_in, const int* in_sizes, int n_in,
                              void* d_out, int out_size, void* d_ws, size_t ws_size,
                              hipStream_t stream)
{
    const float *X, *W;
    if (in_sizes[0] < in_sizes[1]) { X = (const float*)d_in[0]; W = (const float*)d_in[1]; }
    else                           { X = (const float*)d_in[1]; W = (const float*)d_in[0]; }

    float* out  = (float*)d_out;
    float* outv = out;             // v: [B,No,Do] fp32
    float* outc = out + V_ELEMS;   // c: [B,Ni,No] fp32

    const size_t needBig = ((size_t)B_ * CH_ * NOD_ + 2 * (size_t)B_ * NOD_) * sizeof(float);
    if (ws_size < needBig) {       // never expected (ws >= 64 MB measured R12)
        caps_naive<<<B_, 1024, 0, stream>>>(X, W, outv, outc);
        return;
    }

    float* part = (float*)d_ws;                      // 25.2 MB
    float* v0   = part + (size_t)B_ * CH_ * NOD_;
    float* w01  = v0 + (size_t)B_ * NOD_;

    dim3 gP(CH_, BSPLIT_), blk(256), gS(256), blkS(256);
    caps_pass<0><<<gP, blk, 0, stream>>>(X, W, nullptr, part, nullptr);
    caps_squash<0><<<gS, blkS, 0, stream>>>(part, nullptr, v0);
    caps_pass<1><<<gP, blk, 0, stream>>>(X, W, v0, part, nullptr);
    caps_squash<1><<<gS, blkS, 0, stream>>>(part, v0, w01);
    caps_pass<2><<<gP, blk, 0, stream>>>(X, W, w01, part, outc);
    caps_squash<2><<<gS, blkS, 0, stream>>>(part, nullptr, outv);
}